// Round 8
// baseline (319.454 us; speedup 1.0000x reference)
//
#include <hip/hip_runtime.h>
#include <math.h>

#define NTOK 65536
#define CDIM 256
#define DDIM 16
#define KCOD 4096
#define HWSZ 4096

#define DELTA 0.04f   // prune margin on dot scale; bound needs >=0.016

typedef short short8 __attribute__((ext_vector_type(8)));
typedef float f32x16 __attribute__((ext_vector_type(16)));

// ---- ws layout (float offsets) ----
#define WS_ENORM 0                          // [65536] normalized codebook fp32
#define WS_ENN   (WS_ENORM + KCOD*DDIM)     // [4096]  sum(e_norm^2)
#define WS_WDT   (WS_ENN + KCOD)            // [4096]  w_down transposed [c][d]
#define WS_EBF   (WS_WDT + CDIM*DDIM)       // [32768] codebook bf16-packed (8 uints/code)
#define WS_ZN    (WS_EBF + KCOD*8)          // [1048576] z_norm fp32 [N,16]
#define WS_ZNBF  (WS_ZN + NTOK*DDIM)        // [524288] z_norm bf16-packed (8 uints/token)
#define WS_M1    (WS_ZNBF + NTOK*8)         // [65536] per-token max approx dot
#define WS_BCS   (WS_M1 + NTOK)             // [4096]
#define WS_BES   (WS_BCS + KCOD)            // [65536]
#define WS_SCAL  (WS_BES + KCOD*DDIM)       // [8] 0=loss 1=n 2=ent
#define WS_PACK  (WS_SCAL + 8)              // [65536 x u64] packed (score,idx)

// ---- out layout (float offsets) ----
#define OFS_ZQ   0
#define OFS_LOSS 16777216
#define OFS_IDX  16777217
#define OFS_ENT  16842753
#define OFS_NE   16842754
#define OFS_NCS  16908290
#define OFS_NEA  16912386

__device__ inline unsigned f2bf2(float lo, float hi) {
  unsigned a = __float_as_uint(lo), b = __float_as_uint(hi);
  a = (a + 0x7FFFu + ((a >> 16) & 1u)) >> 16;   // RNE to bf16
  b = (b + 0x7FFFu + ((b >> 16) & 1u)) >> 16;
  return a | (b << 16);
}

// ============ normalize codebook + transpose w_down + bf16 codebook ============
__global__ __launch_bounds__(256) void knorm_kernel(const float* __restrict__ emb,
                                                    const float* __restrict__ w_down,
                                                    float* __restrict__ ws) {
  int k = blockIdx.x * 256 + threadIdx.x;
  const float4* src = (const float4*)emb + (size_t)k * 4;
  float4 t0 = src[0], t1 = src[1], t2 = src[2], t3 = src[3];
  float e[16] = {t0.x,t0.y,t0.z,t0.w, t1.x,t1.y,t1.z,t1.w,
                 t2.x,t2.y,t2.z,t2.w, t3.x,t3.y,t3.z,t3.w};
  float ss = 0.f;
  #pragma unroll
  for (int d = 0; d < 16; ++d) ss += e[d] * e[d];
  float dn = fmaxf(sqrtf(ss), 1e-12f);
  #pragma unroll
  for (int d = 0; d < 16; ++d) e[d] = e[d] / dn;
  float s2 = 0.f;
  #pragma unroll
  for (int d = 0; d < 16; ++d) s2 += e[d] * e[d];
  float4* dst = (float4*)(ws + WS_ENORM) + (size_t)k * 4;
  dst[0] = make_float4(e[0],e[1],e[2],e[3]);
  dst[1] = make_float4(e[4],e[5],e[6],e[7]);
  dst[2] = make_float4(e[8],e[9],e[10],e[11]);
  dst[3] = make_float4(e[12],e[13],e[14],e[15]);
  ws[WS_ENN + k] = s2;
  ws[WS_WDT + k] = w_down[(k & 15) * 256 + (k >> 4)];
  // bf16 pack (RNE), 8 uints per code
  uint4 p0 = make_uint4(f2bf2(e[0],e[1]),  f2bf2(e[2],e[3]),
                        f2bf2(e[4],e[5]),  f2bf2(e[6],e[7]));
  uint4 p1 = make_uint4(f2bf2(e[8],e[9]),  f2bf2(e[10],e[11]),
                        f2bf2(e[12],e[13]),f2bf2(e[14],e[15]));
  uint4* eb = (uint4*)(ws + WS_EBF) + (size_t)k * 2;
  eb[0] = p0; eb[1] = p1;
}

// ============ down-proj + L2-normalize + bf16 copy ============
__global__ __launch_bounds__(256) void kdown_kernel(const float* __restrict__ z,
                                                    const float* __restrict__ wdt,
                                                    const float* __restrict__ b_down,
                                                    float* __restrict__ znp,
                                                    unsigned* __restrict__ znbf) {
  const int tid = threadIdx.x;
  const int n = blockIdx.x * 256 + tid;
  const int b = n >> 12;
  const int hw = n & 4095;
  const float* zp = z + (size_t)b * (CDIM * HWSZ) + hw;

  float acc[16];
  #pragma unroll
  for (int d = 0; d < 16; ++d) acc[d] = 0.f;

  #pragma unroll 16
  for (int c = 0; c < CDIM; ++c) {
    float zv = zp[(size_t)c * HWSZ];
    const float4* wr = (const float4*)(wdt + c * 16); // uniform -> s_load
    float4 w0 = wr[0], w1 = wr[1], w2 = wr[2], w3 = wr[3];
    acc[0]  = fmaf(zv, w0.x, acc[0]);  acc[1]  = fmaf(zv, w0.y, acc[1]);
    acc[2]  = fmaf(zv, w0.z, acc[2]);  acc[3]  = fmaf(zv, w0.w, acc[3]);
    acc[4]  = fmaf(zv, w1.x, acc[4]);  acc[5]  = fmaf(zv, w1.y, acc[5]);
    acc[6]  = fmaf(zv, w1.z, acc[6]);  acc[7]  = fmaf(zv, w1.w, acc[7]);
    acc[8]  = fmaf(zv, w2.x, acc[8]);  acc[9]  = fmaf(zv, w2.y, acc[9]);
    acc[10] = fmaf(zv, w2.z, acc[10]); acc[11] = fmaf(zv, w2.w, acc[11]);
    acc[12] = fmaf(zv, w3.x, acc[12]); acc[13] = fmaf(zv, w3.y, acc[13]);
    acc[14] = fmaf(zv, w3.z, acc[14]); acc[15] = fmaf(zv, w3.w, acc[15]);
  }

  #pragma unroll
  for (int d = 0; d < 16; ++d) acc[d] = acc[d] + b_down[d];
  float ss = 0.f;
  #pragma unroll
  for (int d = 0; d < 16; ++d) ss += acc[d] * acc[d];
  float dn = fmaxf(sqrtf(ss), 1e-12f);
  #pragma unroll
  for (int d = 0; d < 16; ++d) acc[d] = acc[d] / dn;

  float4* op = (float4*)znp + (size_t)n * 4;
  op[0] = make_float4(acc[0],acc[1],acc[2],acc[3]);
  op[1] = make_float4(acc[4],acc[5],acc[6],acc[7]);
  op[2] = make_float4(acc[8],acc[9],acc[10],acc[11]);
  op[3] = make_float4(acc[12],acc[13],acc[14],acc[15]);

  uint4 p0 = make_uint4(f2bf2(acc[0],acc[1]),  f2bf2(acc[2],acc[3]),
                        f2bf2(acc[4],acc[5]),  f2bf2(acc[6],acc[7]));
  uint4 p1 = make_uint4(f2bf2(acc[8],acc[9]),  f2bf2(acc[10],acc[11]),
                        f2bf2(acc[12],acc[13]),f2bf2(acc[14],acc[15]));
  uint4* zb = (uint4*)znbf + (size_t)n * 2;
  zb[0] = p0; zb[1] = p1;
}

// ============ pass 1: per-token max approx dot via MFMA ============
// 32x32x16 bf16: A row=lane&31 (token), k=(lane>>5)*8+i; B col=lane&31 (code),
// k same; C/D col=lane&31, row=(reg&3)+8*(reg>>2)+4*(lane>>5)  [m74-verified]
__global__ __launch_bounds__(256) void kmin_kernel(const unsigned* __restrict__ znbf,
                                                   const unsigned* __restrict__ ebf,
                                                   float* __restrict__ m1) {
  const int lane = threadIdx.x & 63;
  const int wv = threadIdx.x >> 6;
  const int tokbase = (blockIdx.x * 4 + wv) * 32;
  const int hi = lane >> 5;
  const int ln = lane & 31;

  const short8* za = (const short8*)znbf;
  const short8* eb = (const short8*)ebf;
  short8 afrag = za[(size_t)(tokbase + ln) * 2 + hi];

  float m[16];
  #pragma unroll
  for (int r = 0; r < 16; ++r) m[r] = -3.4e38f;

  #pragma unroll 2
  for (int kt = 0; kt < 128; ++kt) {
    short8 bfrag = eb[(size_t)(kt * 32 + ln) * 2 + hi];
    f32x16 acc;
    #pragma unroll
    for (int r = 0; r < 16; ++r) acc[r] = 0.f;
    acc = __builtin_amdgcn_mfma_f32_32x32x16_bf16(afrag, bfrag, acc, 0, 0, 0);
    #pragma unroll
    for (int r = 0; r < 16; ++r) m[r] = fmaxf(m[r], acc[r]);
  }

  #pragma unroll
  for (int r = 0; r < 16; ++r) {
    float v = m[r];
    v = fmaxf(v, __shfl_xor(v, 16, 32));
    v = fmaxf(v, __shfl_xor(v, 8, 32));
    v = fmaxf(v, __shfl_xor(v, 4, 32));
    v = fmaxf(v, __shfl_xor(v, 2, 32));
    v = fmaxf(v, __shfl_xor(v, 1, 32));
    m[r] = v;
  }
  if (ln == 0) {
    #pragma unroll
    for (int r = 0; r < 16; ++r) {
      int row = (r & 3) + 8 * (r >> 2) + 4 * hi;
      m1[tokbase + row] = m[r];
    }
  }
}

// ============ pass 2: flag candidates, exact fp32 recheck + atomicMin ============
__global__ __launch_bounds__(256) void kcand_kernel(const unsigned* __restrict__ znbf,
                                                    const unsigned* __restrict__ ebf,
                                                    const float* __restrict__ m1,
                                                    const float* __restrict__ enorm,
                                                    const float* __restrict__ ennp,
                                                    const float* __restrict__ znp,
                                                    unsigned long long* __restrict__ packp) {
  const int lane = threadIdx.x & 63;
  const int wv = threadIdx.x >> 6;
  const int tokbase = (blockIdx.x * 4 + wv) * 32;
  const int hi = lane >> 5;
  const int ln = lane & 31;

  const short8* za = (const short8*)znbf;
  const short8* eb = (const short8*)ebf;
  short8 afrag = za[(size_t)(tokbase + ln) * 2 + hi];

  float thr[16];
  #pragma unroll
  for (int r = 0; r < 16; ++r) {
    int row = (r & 3) + 8 * (r >> 2) + 4 * hi;
    thr[r] = m1[tokbase + row] - DELTA;
  }

  for (int kt = 0; kt < 128; ++kt) {
    short8 bfrag = eb[(size_t)(kt * 32 + ln) * 2 + hi];
    f32x16 acc;
    #pragma unroll
    for (int r = 0; r < 16; ++r) acc[r] = 0.f;
    acc = __builtin_amdgcn_mfma_f32_32x32x16_bf16(afrag, bfrag, acc, 0, 0, 0);

    unsigned flags = 0u;
    #pragma unroll
    for (int r = 0; r < 16; ++r) flags |= (acc[r] >= thr[r]) ? (1u << r) : 0u;

    if (flags) {
      #pragma unroll
      for (int r = 0; r < 16; ++r) {
        if (flags & (1u << r)) {
          int row = (r & 3) + 8 * (r >> 2) + 4 * hi;
          int token = tokbase + row;
          int code = kt * 32 + ln;
          const float* znr = znp + (size_t)token * 16;
          const float* er  = enorm + (size_t)code * 16;
          float dsc = ennp[code];
          #pragma unroll
          for (int i = 0; i < 16; ++i) dsc = fmaf(-2.f * znr[i], er[i], dsc);
          unsigned u = __float_as_uint(dsc);
          u = (u & 0x80000000u) ? ~u : (u | 0x80000000u);
          unsigned long long key =
              ((unsigned long long)u << 32) | (unsigned)code;
          atomicMin(packp + token, key);
        }
      }
    }
  }
}

// ============ merge + scatter + loss + fused up-proj ============
__global__ __launch_bounds__(256) void kfinal_kernel(const float* __restrict__ w_up,
                                                     const float* __restrict__ b_up,
                                                     const float* __restrict__ enorm,
                                                     const float* __restrict__ znp,
                                                     const unsigned long long* __restrict__ packp,
                                                     float* __restrict__ wsacc,
                                                     float* __restrict__ out) {
  const int tid = threadIdx.x;
  const int n = blockIdx.x * 256 + tid;
  const int bidx = (int)(unsigned)(packp[n] & 0xFFFFFFFFull);

  float zn[16];
  {
    const float4* zp = (const float4*)znp + (size_t)n * 4;
    float4 a0 = zp[0], a1 = zp[1], a2 = zp[2], a3 = zp[3];
    zn[0]=a0.x; zn[1]=a0.y; zn[2]=a0.z; zn[3]=a0.w;
    zn[4]=a1.x; zn[5]=a1.y; zn[6]=a1.z; zn[7]=a1.w;
    zn[8]=a2.x; zn[9]=a2.y; zn[10]=a2.z; zn[11]=a2.w;
    zn[12]=a3.x; zn[13]=a3.y; zn[14]=a3.z; zn[15]=a3.w;
  }
  float zq[16];
  {
    const float4* ebp = (const float4*)enorm + (size_t)bidx * 4;
    float4 q0 = ebp[0], q1 = ebp[1], q2 = ebp[2], q3 = ebp[3];
    zq[0]=q0.x; zq[1]=q0.y; zq[2]=q0.z; zq[3]=q0.w;
    zq[4]=q1.x; zq[5]=q1.y; zq[6]=q1.z; zq[7]=q1.w;
    zq[8]=q2.x; zq[9]=q2.y; zq[10]=q2.z; zq[11]=q2.w;
    zq[12]=q3.x; zq[13]=q3.y; zq[14]=q3.z; zq[15]=q3.w;
  }

  out[OFS_IDX + n] = (float)bidx;

  float ls = 0.f;
  #pragma unroll
  for (int d = 0; d < 16; ++d) { float df = zn[d] - zq[d]; ls = fmaf(df, df, ls); }

  atomicAdd(wsacc + bidx, 1.0f);
  #pragma unroll
  for (int d = 0; d < 16; ++d)
    atomicAdd(wsacc + KCOD + (size_t)bidx * 16 + d, zn[d]);

  #pragma unroll
  for (int off = 32; off > 0; off >>= 1) ls += __shfl_down(ls, off, 64);
  if ((tid & 63) == 0) atomicAdd(wsacc + KCOD + KCOD * DDIM + 0, ls);

  float ql[16];
  #pragma unroll
  for (int d = 0; d < 16; ++d) ql[d] = zn[d] + (zq[d] - zn[d]);

  const int b = n >> 12, hw = n & 4095;
  float* op = out + OFS_ZQ + (size_t)b * (CDIM * HWSZ) + hw;
  #pragma unroll 8
  for (int c = 0; c < CDIM; ++c) {
    const float4* wr = (const float4*)(w_up + c * 16); // uniform -> s_load
    float4 w0 = wr[0], w1 = wr[1], w2 = wr[2], w3 = wr[3];
    float a = 0.f;
    a = fmaf(ql[0],  w0.x, a); a = fmaf(ql[1],  w0.y, a);
    a = fmaf(ql[2],  w0.z, a); a = fmaf(ql[3],  w0.w, a);
    a = fmaf(ql[4],  w1.x, a); a = fmaf(ql[5],  w1.y, a);
    a = fmaf(ql[6],  w1.z, a); a = fmaf(ql[7],  w1.w, a);
    a = fmaf(ql[8],  w2.x, a); a = fmaf(ql[9],  w2.y, a);
    a = fmaf(ql[10], w2.z, a); a = fmaf(ql[11], w2.w, a);
    a = fmaf(ql[12], w3.x, a); a = fmaf(ql[13], w3.y, a);
    a = fmaf(ql[14], w3.z, a); a = fmaf(ql[15], w3.w, a);
    a = a + b_up[c];
    op[(size_t)c * HWSZ] = a;
  }
}

// ============ EMA buffers + partial sums (n, entropy) ============
__global__ __launch_bounds__(256) void kema_kernel(const float* __restrict__ cluster_size,
                                                   const float* __restrict__ embed_avg,
                                                   float* __restrict__ ws,
                                                   float* __restrict__ out) {
  const float DEC = 0.99f;
  const float OMD = (float)(1.0 - 0.99);
  const int k = blockIdx.x * 256 + threadIdx.x;
  float bcsv = ws[WS_BCS + k];
  float ncs = cluster_size[k] * DEC + OMD * bcsv;
  out[OFS_NCS + k] = ncs;
  #pragma unroll
  for (int d = 0; d < 16; ++d) {
    float nea = embed_avg[(size_t)k * 16 + d] * DEC + OMD * ws[WS_BES + (size_t)k * 16 + d];
    out[OFS_NEA + (size_t)k * 16 + d] = nea;
  }
  float p = bcsv / 65536.0f;
  float et = -p * logf(p + 1e-8f);

  __shared__ float r1[4], r2[4];
  float v1 = ncs, v2 = et;
  #pragma unroll
  for (int off = 32; off > 0; off >>= 1) {
    v1 += __shfl_down(v1, off, 64);
    v2 += __shfl_down(v2, off, 64);
  }
  int lane = threadIdx.x & 63, w = threadIdx.x >> 6;
  if (lane == 0) { r1[w] = v1; r2[w] = v2; }
  __syncthreads();
  if (threadIdx.x == 0) {
    atomicAdd(ws + WS_SCAL + 1, (r1[0] + r1[1]) + (r1[2] + r1[3]));
    atomicAdd(ws + WS_SCAL + 2, (r2[0] + r2[1]) + (r2[2] + r2[3]));
  }
}

// ============ new_embedding + scalar outputs ============
__global__ __launch_bounds__(256) void kemb_kernel(const float* __restrict__ ws,
                                                   float* __restrict__ out) {
  const float KEPS = (float)(4096.0 * 1e-5);
  const int k = blockIdx.x * 256 + threadIdx.x;
  float n = ws[WS_SCAL + 1];
  float ncs = out[OFS_NCS + k];
  float cs = (ncs + 1e-5f) / (n + KEPS) * n;
  #pragma unroll
  for (int d = 0; d < 16; ++d)
    out[OFS_NE + (size_t)k * 16 + d] = out[OFS_NEA + (size_t)k * 16 + d] / cs;
  if (k == 0) {
    out[OFS_LOSS] = 0.25f * (ws[WS_SCAL + 0] / 1048576.0f);
    out[OFS_ENT]  = (float)8.317766166719343 - ws[WS_SCAL + 2];
  }
}

extern "C" void kernel_launch(void* const* d_in, const int* in_sizes, int n_in,
                              void* d_out, int out_size, void* d_ws, size_t ws_size,
                              hipStream_t stream) {
  const float* z        = (const float*)d_in[0];
  const float* w_down   = (const float*)d_in[1];
  const float* b_down   = (const float*)d_in[2];
  const float* w_up     = (const float*)d_in[3];
  const float* b_up     = (const float*)d_in[4];
  const float* emb      = (const float*)d_in[5];
  const float* csz      = (const float*)d_in[6];
  const float* eavg     = (const float*)d_in[7];
  float* out = (float*)d_out;
  float* ws  = (float*)d_ws;

  hipMemsetAsync(ws + WS_BCS, 0, (size_t)(KCOD + KCOD*DDIM + 8) * sizeof(float), stream);
  hipMemsetAsync(ws + WS_PACK, 0xFF, (size_t)NTOK * 8, stream);

  knorm_kernel<<<KCOD / 256, 256, 0, stream>>>(emb, w_down, ws);
  kdown_kernel<<<NTOK / 256, 256, 0, stream>>>(z, ws + WS_WDT, b_down,
                                               ws + WS_ZN, (unsigned*)(ws + WS_ZNBF));
  kmin_kernel<<<NTOK / 128, 256, 0, stream>>>((const unsigned*)(ws + WS_ZNBF),
                                              (const unsigned*)(ws + WS_EBF),
                                              ws + WS_M1);
  kcand_kernel<<<NTOK / 128, 256, 0, stream>>>((const unsigned*)(ws + WS_ZNBF),
                                               (const unsigned*)(ws + WS_EBF),
                                               ws + WS_M1, ws + WS_ENORM, ws + WS_ENN,
                                               ws + WS_ZN,
                                               (unsigned long long*)(ws + WS_PACK));
  kfinal_kernel<<<NTOK / 256, 256, 0, stream>>>(
      w_up, b_up, ws + WS_ENORM, ws + WS_ZN,
      (const unsigned long long*)(ws + WS_PACK), ws + WS_BCS, out);
  kema_kernel<<<KCOD / 256, 256, 0, stream>>>(csz, eavg, ws, out);
  kemb_kernel<<<KCOD / 256, 256, 0, stream>>>(ws, out);
}

// Round 9
// 274.970 us; speedup vs baseline: 1.1618x; 1.1618x over previous
//
#include <hip/hip_runtime.h>
#include <math.h>

#define NTOK 65536
#define CDIM 256
#define DDIM 16
#define KCOD 4096
#define HWSZ 4096

#define DELTA 0.04f   // prune margin; bf16 bound is ~0.004, 10x safety
#define KSPLIT2 8
#define KTPS (KCOD / 32 / KSPLIT2)  // 16 MFMA k-tiles per split

typedef short short8 __attribute__((ext_vector_type(8)));
typedef float f32x16 __attribute__((ext_vector_type(16)));

// ---- ws layout (float offsets) ----
#define WS_ENORM 0                          // [65536] normalized codebook fp32
#define WS_ENN   (WS_ENORM + KCOD*DDIM)     // [4096]  sum(e_norm^2)
#define WS_WDT   (WS_ENN + KCOD)            // [4096]  w_down transposed [c][d]
#define WS_EBF   (WS_WDT + CDIM*DDIM)       // [32768] codebook bf16 (8 uints/code)
#define WS_ZN    (WS_EBF + KCOD*8)          // [1048576] z_norm fp32 [N,16]
#define WS_ZNBF  (WS_ZN + NTOK*DDIM)        // [524288] z_norm bf16 (8 uints/token)
#define WS_M1    (WS_ZNBF + NTOK*8)         // [65536] per-token max dot (flipped uint)
#define WS_BCS   (WS_M1 + NTOK)             // [4096]
#define WS_BES   (WS_BCS + KCOD)            // [65536]
#define WS_SCAL  (WS_BES + KCOD*DDIM)       // [8] 0=loss 1=n 2=ent
#define WS_PACK  (WS_SCAL + 8)              // [65536 x u64] packed (score,idx)

// ---- out layout (float offsets) ----
#define OFS_ZQ   0
#define OFS_LOSS 16777216
#define OFS_IDX  16777217
#define OFS_ENT  16842753
#define OFS_NE   16842754
#define OFS_NCS  16908290
#define OFS_NEA  16912386

__device__ inline unsigned f2bf2(float lo, float hi) {
  unsigned a = __float_as_uint(lo), b = __float_as_uint(hi);
  a = (a + 0x7FFFu + ((a >> 16) & 1u)) >> 16;   // RNE to bf16
  b = (b + 0x7FFFu + ((b >> 16) & 1u)) >> 16;
  return a | (b << 16);
}
__device__ inline unsigned flipf(float f) {
  unsigned u = __float_as_uint(f);
  return (u & 0x80000000u) ? ~u : (u | 0x80000000u);
}
__device__ inline float unflipf(unsigned k) {
  unsigned u = (k & 0x80000000u) ? (k ^ 0x80000000u) : ~k;
  return __uint_as_float(u);
}

// ============ normalize codebook + transpose w_down + bf16 codebook ============
__global__ __launch_bounds__(256) void knorm_kernel(const float* __restrict__ emb,
                                                    const float* __restrict__ w_down,
                                                    float* __restrict__ ws) {
  int k = blockIdx.x * 256 + threadIdx.x;
  const float4* src = (const float4*)emb + (size_t)k * 4;
  float4 t0 = src[0], t1 = src[1], t2 = src[2], t3 = src[3];
  float e[16] = {t0.x,t0.y,t0.z,t0.w, t1.x,t1.y,t1.z,t1.w,
                 t2.x,t2.y,t2.z,t2.w, t3.x,t3.y,t3.z,t3.w};
  float ss = 0.f;
  #pragma unroll
  for (int d = 0; d < 16; ++d) ss += e[d] * e[d];
  float dn = fmaxf(sqrtf(ss), 1e-12f);
  #pragma unroll
  for (int d = 0; d < 16; ++d) e[d] = e[d] / dn;
  float s2 = 0.f;
  #pragma unroll
  for (int d = 0; d < 16; ++d) s2 += e[d] * e[d];
  float4* dst = (float4*)(ws + WS_ENORM) + (size_t)k * 4;
  dst[0] = make_float4(e[0],e[1],e[2],e[3]);
  dst[1] = make_float4(e[4],e[5],e[6],e[7]);
  dst[2] = make_float4(e[8],e[9],e[10],e[11]);
  dst[3] = make_float4(e[12],e[13],e[14],e[15]);
  ws[WS_ENN + k] = s2;
  ws[WS_WDT + k] = w_down[(k & 15) * 256 + (k >> 4)];
  uint4 p0 = make_uint4(f2bf2(e[0],e[1]),  f2bf2(e[2],e[3]),
                        f2bf2(e[4],e[5]),  f2bf2(e[6],e[7]));
  uint4 p1 = make_uint4(f2bf2(e[8],e[9]),  f2bf2(e[10],e[11]),
                        f2bf2(e[12],e[13]),f2bf2(e[14],e[15]));
  uint4* eb = (uint4*)(ws + WS_EBF) + (size_t)k * 2;
  eb[0] = p0; eb[1] = p1;
}

// ============ down-proj + L2-normalize + bf16 copy ============
__global__ __launch_bounds__(256) void kdown_kernel(const float* __restrict__ z,
                                                    const float* __restrict__ wdt,
                                                    const float* __restrict__ b_down,
                                                    float* __restrict__ znp,
                                                    unsigned* __restrict__ znbf) {
  const int tid = threadIdx.x;
  const int n = blockIdx.x * 256 + tid;
  const int b = n >> 12;
  const int hw = n & 4095;
  const float* zp = z + (size_t)b * (CDIM * HWSZ) + hw;

  float acc[16];
  #pragma unroll
  for (int d = 0; d < 16; ++d) acc[d] = 0.f;

  #pragma unroll 16
  for (int c = 0; c < CDIM; ++c) {
    float zv = zp[(size_t)c * HWSZ];
    const float4* wr = (const float4*)(wdt + c * 16); // uniform -> s_load
    float4 w0 = wr[0], w1 = wr[1], w2 = wr[2], w3 = wr[3];
    acc[0]  = fmaf(zv, w0.x, acc[0]);  acc[1]  = fmaf(zv, w0.y, acc[1]);
    acc[2]  = fmaf(zv, w0.z, acc[2]);  acc[3]  = fmaf(zv, w0.w, acc[3]);
    acc[4]  = fmaf(zv, w1.x, acc[4]);  acc[5]  = fmaf(zv, w1.y, acc[5]);
    acc[6]  = fmaf(zv, w1.z, acc[6]);  acc[7]  = fmaf(zv, w1.w, acc[7]);
    acc[8]  = fmaf(zv, w2.x, acc[8]);  acc[9]  = fmaf(zv, w2.y, acc[9]);
    acc[10] = fmaf(zv, w2.z, acc[10]); acc[11] = fmaf(zv, w2.w, acc[11]);
    acc[12] = fmaf(zv, w3.x, acc[12]); acc[13] = fmaf(zv, w3.y, acc[13]);
    acc[14] = fmaf(zv, w3.z, acc[14]); acc[15] = fmaf(zv, w3.w, acc[15]);
  }

  #pragma unroll
  for (int d = 0; d < 16; ++d) acc[d] = acc[d] + b_down[d];
  float ss = 0.f;
  #pragma unroll
  for (int d = 0; d < 16; ++d) ss += acc[d] * acc[d];
  float dn = fmaxf(sqrtf(ss), 1e-12f);
  #pragma unroll
  for (int d = 0; d < 16; ++d) acc[d] = acc[d] / dn;

  float4* op = (float4*)znp + (size_t)n * 4;
  op[0] = make_float4(acc[0],acc[1],acc[2],acc[3]);
  op[1] = make_float4(acc[4],acc[5],acc[6],acc[7]);
  op[2] = make_float4(acc[8],acc[9],acc[10],acc[11]);
  op[3] = make_float4(acc[12],acc[13],acc[14],acc[15]);

  uint4 p0 = make_uint4(f2bf2(acc[0],acc[1]),  f2bf2(acc[2],acc[3]),
                        f2bf2(acc[4],acc[5]),  f2bf2(acc[6],acc[7]));
  uint4 p1 = make_uint4(f2bf2(acc[8],acc[9]),  f2bf2(acc[10],acc[11]),
                        f2bf2(acc[12],acc[13]),f2bf2(acc[14],acc[15]));
  uint4* zb = (uint4*)znbf + (size_t)n * 2;
  zb[0] = p0; zb[1] = p1;
}

// ============ pass 1: per-token max approx dot, K split 8 ways ============
// 32x32x16 bf16 C/D: col=lane&31, row=(reg&3)+8*(reg>>2)+4*(lane>>5) [m74]
__global__ __launch_bounds__(256) void kmin_kernel(const unsigned* __restrict__ znbf,
                                                   const unsigned* __restrict__ ebf,
                                                   unsigned* __restrict__ m1u) {
  const int lane = threadIdx.x & 63;
  const int wv = threadIdx.x >> 6;
  const int tokbase = (blockIdx.x * 4 + wv) * 32;
  const int kt0 = blockIdx.y * KTPS;
  const int hi = lane >> 5;
  const int ln = lane & 31;

  const short8* za = (const short8*)znbf;
  const short8* eb = (const short8*)ebf;
  short8 afrag = za[(size_t)(tokbase + ln) * 2 + hi];

  float m[16];
  #pragma unroll
  for (int r = 0; r < 16; ++r) m[r] = -3.4e38f;

  #pragma unroll 4
  for (int kt = 0; kt < KTPS; ++kt) {
    short8 bfrag = eb[(size_t)((kt0 + kt) * 32 + ln) * 2 + hi];
    f32x16 acc;
    #pragma unroll
    for (int r = 0; r < 16; ++r) acc[r] = 0.f;
    acc = __builtin_amdgcn_mfma_f32_32x32x16_bf16(afrag, bfrag, acc, 0, 0, 0);
    #pragma unroll
    for (int r = 0; r < 16; ++r) m[r] = fmaxf(m[r], acc[r]);
  }

  #pragma unroll
  for (int r = 0; r < 16; ++r) {
    float v = m[r];
    v = fmaxf(v, __shfl_xor(v, 16, 32));
    v = fmaxf(v, __shfl_xor(v, 8, 32));
    v = fmaxf(v, __shfl_xor(v, 4, 32));
    v = fmaxf(v, __shfl_xor(v, 2, 32));
    v = fmaxf(v, __shfl_xor(v, 1, 32));
    m[r] = v;
  }
  if (ln == 0) {
    #pragma unroll
    for (int r = 0; r < 16; ++r) {
      int row = (r & 3) + 8 * (r >> 2) + 4 * hi;
      atomicMax(m1u + tokbase + row, flipf(m[r]));
    }
  }
}

// ============ pass 2: flag candidates, exact fp32 recheck + atomicMin ============
__global__ __launch_bounds__(256) void kcand_kernel(const unsigned* __restrict__ znbf,
                                                    const unsigned* __restrict__ ebf,
                                                    const unsigned* __restrict__ m1u,
                                                    const float* __restrict__ enorm,
                                                    const float* __restrict__ ennp,
                                                    const float* __restrict__ znp,
                                                    unsigned long long* __restrict__ packp) {
  const int lane = threadIdx.x & 63;
  const int wv = threadIdx.x >> 6;
  const int tokbase = (blockIdx.x * 4 + wv) * 32;
  const int kt0 = blockIdx.y * KTPS;
  const int hi = lane >> 5;
  const int ln = lane & 31;

  const short8* za = (const short8*)znbf;
  const short8* eb = (const short8*)ebf;
  short8 afrag = za[(size_t)(tokbase + ln) * 2 + hi];

  float thr[16];
  #pragma unroll
  for (int r = 0; r < 16; ++r) {
    int row = (r & 3) + 8 * (r >> 2) + 4 * hi;
    thr[r] = unflipf(m1u[tokbase + row]) - DELTA;
  }

  for (int kt = 0; kt < KTPS; ++kt) {
    short8 bfrag = eb[(size_t)((kt0 + kt) * 32 + ln) * 2 + hi];
    f32x16 acc;
    #pragma unroll
    for (int r = 0; r < 16; ++r) acc[r] = 0.f;
    acc = __builtin_amdgcn_mfma_f32_32x32x16_bf16(afrag, bfrag, acc, 0, 0, 0);

    unsigned flags = 0u;
    #pragma unroll
    for (int r = 0; r < 16; ++r) flags |= (acc[r] >= thr[r]) ? (1u << r) : 0u;

    if (flags) {
      #pragma unroll
      for (int r = 0; r < 16; ++r) {
        if (flags & (1u << r)) {
          int row = (r & 3) + 8 * (r >> 2) + 4 * hi;
          int token = tokbase + row;
          int code = (kt0 + kt) * 32 + ln;
          const float4* znr4 = (const float4*)znp + (size_t)token * 4;
          const float4* er4  = (const float4*)enorm + (size_t)code * 4;
          float4 za0 = znr4[0], za1 = znr4[1], za2 = znr4[2], za3 = znr4[3];
          float4 eb0 = er4[0],  eb1 = er4[1],  eb2 = er4[2],  eb3 = er4[3];
          float dsc = ennp[code];
          dsc = fmaf(-2.f * za0.x, eb0.x, dsc); dsc = fmaf(-2.f * za0.y, eb0.y, dsc);
          dsc = fmaf(-2.f * za0.z, eb0.z, dsc); dsc = fmaf(-2.f * za0.w, eb0.w, dsc);
          dsc = fmaf(-2.f * za1.x, eb1.x, dsc); dsc = fmaf(-2.f * za1.y, eb1.y, dsc);
          dsc = fmaf(-2.f * za1.z, eb1.z, dsc); dsc = fmaf(-2.f * za1.w, eb1.w, dsc);
          dsc = fmaf(-2.f * za2.x, eb2.x, dsc); dsc = fmaf(-2.f * za2.y, eb2.y, dsc);
          dsc = fmaf(-2.f * za2.z, eb2.z, dsc); dsc = fmaf(-2.f * za2.w, eb2.w, dsc);
          dsc = fmaf(-2.f * za3.x, eb3.x, dsc); dsc = fmaf(-2.f * za3.y, eb3.y, dsc);
          dsc = fmaf(-2.f * za3.z, eb3.z, dsc); dsc = fmaf(-2.f * za3.w, eb3.w, dsc);
          unsigned u = __float_as_uint(dsc);
          u = (u & 0x80000000u) ? ~u : (u | 0x80000000u);
          unsigned long long key =
              ((unsigned long long)u << 32) | (unsigned)code;
          atomicMin(packp + token, key);
        }
      }
    }
  }
}

// ============ merge + scatter + loss + fused up-proj ============
__global__ __launch_bounds__(256) void kfinal_kernel(const float* __restrict__ w_up,
                                                     const float* __restrict__ b_up,
                                                     const float* __restrict__ enorm,
                                                     const float* __restrict__ znp,
                                                     const unsigned long long* __restrict__ packp,
                                                     float* __restrict__ wsacc,
                                                     float* __restrict__ out) {
  const int tid = threadIdx.x;
  const int n = blockIdx.x * 256 + tid;
  const int bidx = (int)(unsigned)(packp[n] & 0xFFFFFFFFull);

  float zn[16];
  {
    const float4* zp = (const float4*)znp + (size_t)n * 4;
    float4 a0 = zp[0], a1 = zp[1], a2 = zp[2], a3 = zp[3];
    zn[0]=a0.x; zn[1]=a0.y; zn[2]=a0.z; zn[3]=a0.w;
    zn[4]=a1.x; zn[5]=a1.y; zn[6]=a1.z; zn[7]=a1.w;
    zn[8]=a2.x; zn[9]=a2.y; zn[10]=a2.z; zn[11]=a2.w;
    zn[12]=a3.x; zn[13]=a3.y; zn[14]=a3.z; zn[15]=a3.w;
  }
  float zq[16];
  {
    const float4* ebp = (const float4*)enorm + (size_t)bidx * 4;
    float4 q0 = ebp[0], q1 = ebp[1], q2 = ebp[2], q3 = ebp[3];
    zq[0]=q0.x; zq[1]=q0.y; zq[2]=q0.z; zq[3]=q0.w;
    zq[4]=q1.x; zq[5]=q1.y; zq[6]=q1.z; zq[7]=q1.w;
    zq[8]=q2.x; zq[9]=q2.y; zq[10]=q2.z; zq[11]=q2.w;
    zq[12]=q3.x; zq[13]=q3.y; zq[14]=q3.z; zq[15]=q3.w;
  }

  out[OFS_IDX + n] = (float)bidx;

  float ls = 0.f;
  #pragma unroll
  for (int d = 0; d < 16; ++d) { float df = zn[d] - zq[d]; ls = fmaf(df, df, ls); }

  atomicAdd(wsacc + bidx, 1.0f);
  #pragma unroll
  for (int d = 0; d < 16; ++d)
    atomicAdd(wsacc + KCOD + (size_t)bidx * 16 + d, zn[d]);

  #pragma unroll
  for (int off = 32; off > 0; off >>= 1) ls += __shfl_down(ls, off, 64);
  if ((tid & 63) == 0) atomicAdd(wsacc + KCOD + KCOD * DDIM + 0, ls);

  float ql[16];
  #pragma unroll
  for (int d = 0; d < 16; ++d) ql[d] = zn[d] + (zq[d] - zn[d]);

  const int b = n >> 12, hw = n & 4095;
  float* op = out + OFS_ZQ + (size_t)b * (CDIM * HWSZ) + hw;
  #pragma unroll 8
  for (int c = 0; c < CDIM; ++c) {
    const float4* wr = (const float4*)(w_up + c * 16); // uniform -> s_load
    float4 w0 = wr[0], w1 = wr[1], w2 = wr[2], w3 = wr[3];
    float a = 0.f;
    a = fmaf(ql[0],  w0.x, a); a = fmaf(ql[1],  w0.y, a);
    a = fmaf(ql[2],  w0.z, a); a = fmaf(ql[3],  w0.w, a);
    a = fmaf(ql[4],  w1.x, a); a = fmaf(ql[5],  w1.y, a);
    a = fmaf(ql[6],  w1.z, a); a = fmaf(ql[7],  w1.w, a);
    a = fmaf(ql[8],  w2.x, a); a = fmaf(ql[9],  w2.y, a);
    a = fmaf(ql[10], w2.z, a); a = fmaf(ql[11], w2.w, a);
    a = fmaf(ql[12], w3.x, a); a = fmaf(ql[13], w3.y, a);
    a = fmaf(ql[14], w3.z, a); a = fmaf(ql[15], w3.w, a);
    a = a + b_up[c];
    op[(size_t)c * HWSZ] = a;
  }
}

// ============ EMA buffers + partial sums (n, entropy) ============
__global__ __launch_bounds__(256) void kema_kernel(const float* __restrict__ cluster_size,
                                                   const float* __restrict__ embed_avg,
                                                   float* __restrict__ ws,
                                                   float* __restrict__ out) {
  const float DEC = 0.99f;
  const float OMD = (float)(1.0 - 0.99);
  const int k = blockIdx.x * 256 + threadIdx.x;
  float bcsv = ws[WS_BCS + k];
  float ncs = cluster_size[k] * DEC + OMD * bcsv;
  out[OFS_NCS + k] = ncs;
  #pragma unroll
  for (int d = 0; d < 16; ++d) {
    float nea = embed_avg[(size_t)k * 16 + d] * DEC + OMD * ws[WS_BES + (size_t)k * 16 + d];
    out[OFS_NEA + (size_t)k * 16 + d] = nea;
  }
  float p = bcsv / 65536.0f;
  float et = -p * logf(p + 1e-8f);

  __shared__ float r1[4], r2[4];
  float v1 = ncs, v2 = et;
  #pragma unroll
  for (int off = 32; off > 0; off >>= 1) {
    v1 += __shfl_down(v1, off, 64);
    v2 += __shfl_down(v2, off, 64);
  }
  int lane = threadIdx.x & 63, w = threadIdx.x >> 6;
  if (lane == 0) { r1[w] = v1; r2[w] = v2; }
  __syncthreads();
  if (threadIdx.x == 0) {
    atomicAdd(ws + WS_SCAL + 1, (r1[0] + r1[1]) + (r1[2] + r1[3]));
    atomicAdd(ws + WS_SCAL + 2, (r2[0] + r2[1]) + (r2[2] + r2[3]));
  }
}

// ============ new_embedding + scalar outputs ============
__global__ __launch_bounds__(256) void kemb_kernel(const float* __restrict__ ws,
                                                   float* __restrict__ out) {
  const float KEPS = (float)(4096.0 * 1e-5);
  const int k = blockIdx.x * 256 + threadIdx.x;
  float n = ws[WS_SCAL + 1];
  float ncs = out[OFS_NCS + k];
  float cs = (ncs + 1e-5f) / (n + KEPS) * n;
  #pragma unroll
  for (int d = 0; d < 16; ++d)
    out[OFS_NE + (size_t)k * 16 + d] = out[OFS_NEA + (size_t)k * 16 + d] / cs;
  if (k == 0) {
    out[OFS_LOSS] = 0.25f * (ws[WS_SCAL + 0] / 1048576.0f);
    out[OFS_ENT]  = (float)8.317766166719343 - ws[WS_SCAL + 2];
  }
}

extern "C" void kernel_launch(void* const* d_in, const int* in_sizes, int n_in,
                              void* d_out, int out_size, void* d_ws, size_t ws_size,
                              hipStream_t stream) {
  const float* z        = (const float*)d_in[0];
  const float* w_down   = (const float*)d_in[1];
  const float* b_down   = (const float*)d_in[2];
  const float* w_up     = (const float*)d_in[3];
  const float* b_up     = (const float*)d_in[4];
  const float* emb      = (const float*)d_in[5];
  const float* csz      = (const float*)d_in[6];
  const float* eavg     = (const float*)d_in[7];
  float* out = (float*)d_out;
  float* ws  = (float*)d_ws;

  // zero m1 (flipped-uint identity) + bcs + bes + scal in one shot
  hipMemsetAsync(ws + WS_M1, 0,
                 (size_t)(NTOK + KCOD + KCOD*DDIM + 8) * sizeof(float), stream);
  hipMemsetAsync(ws + WS_PACK, 0xFF, (size_t)NTOK * 8, stream);

  knorm_kernel<<<KCOD / 256, 256, 0, stream>>>(emb, w_down, ws);
  kdown_kernel<<<NTOK / 256, 256, 0, stream>>>(z, ws + WS_WDT, b_down,
                                               ws + WS_ZN, (unsigned*)(ws + WS_ZNBF));
  kmin_kernel<<<dim3(NTOK / 128, KSPLIT2), 256, 0, stream>>>(
      (const unsigned*)(ws + WS_ZNBF), (const unsigned*)(ws + WS_EBF),
      (unsigned*)(ws + WS_M1));
  kcand_kernel<<<dim3(NTOK / 128, KSPLIT2), 256, 0, stream>>>(
      (const unsigned*)(ws + WS_ZNBF), (const unsigned*)(ws + WS_EBF),
      (const unsigned*)(ws + WS_M1), ws + WS_ENORM, ws + WS_ENN, ws + WS_ZN,
      (unsigned long long*)(ws + WS_PACK));
  kfinal_kernel<<<NTOK / 256, 256, 0, stream>>>(
      w_up, b_up, ws + WS_ENORM, ws + WS_ZN,
      (const unsigned long long*)(ws + WS_PACK), ws + WS_BCS, out);
  kema_kernel<<<KCOD / 256, 256, 0, stream>>>(csz, eavg, ws, out);
  kemb_kernel<<<KCOD / 256, 256, 0, stream>>>(ws, out);
}

// Round 10
// 270.343 us; speedup vs baseline: 1.1817x; 1.0171x over previous
//
#include <hip/hip_runtime.h>
#include <math.h>

#define NTOK 65536
#define CDIM 256
#define DDIM 16
#define KCOD 4096
#define HWSZ 4096

#define DELTA 0.04f   // prune margin; bf16 bound is ~0.004, 10x safety
#define KSPLIT2 8
#define KTPS (KCOD / 32 / KSPLIT2)  // 16 MFMA k-tiles per split

typedef short short8 __attribute__((ext_vector_type(8)));
typedef float f32x16 __attribute__((ext_vector_type(16)));

// ---- ws layout (float offsets) ----
#define WS_ENORM 0                          // [65536] normalized codebook fp32
#define WS_ENN   (WS_ENORM + KCOD*DDIM)     // [4096]  sum(e_norm^2)
#define WS_WDT   (WS_ENN + KCOD)            // [4096]  w_down transposed [c][d]
#define WS_EBF   (WS_WDT + CDIM*DDIM)       // [32768] codebook bf16 (8 uints/code)
#define WS_ZN    (WS_EBF + KCOD*8)          // [1048576] z_norm fp32 [N,16]
#define WS_ZNBF  (WS_ZN + NTOK*DDIM)        // [524288] z_norm bf16 (8 uints/token)
#define WS_M1    (WS_ZNBF + NTOK*8)         // [65536] per-token max dot (flipped uint)
#define WS_BCS   (WS_M1 + NTOK)             // [4096]
#define WS_BES   (WS_BCS + KCOD)            // [65536]
#define WS_SCAL  (WS_BES + KCOD*DDIM)       // [8] 0=loss 1=n 2=ent
#define WS_PACK  (WS_SCAL + 8)              // [65536 x u64] packed (score,idx)

// ---- out layout (float offsets) ----
#define OFS_ZQ   0
#define OFS_LOSS 16777216
#define OFS_IDX  16777217
#define OFS_ENT  16842753
#define OFS_NE   16842754
#define OFS_NCS  16908290
#define OFS_NEA  16912386

__device__ inline unsigned f2bf2(float lo, float hi) {
  unsigned a = __float_as_uint(lo), b = __float_as_uint(hi);
  a = (a + 0x7FFFu + ((a >> 16) & 1u)) >> 16;   // RNE to bf16
  b = (b + 0x7FFFu + ((b >> 16) & 1u)) >> 16;
  return a | (b << 16);
}
__device__ inline unsigned flipf(float f) {
  unsigned u = __float_as_uint(f);
  return (u & 0x80000000u) ? ~u : (u | 0x80000000u);
}
__device__ inline float unflipf(unsigned k) {
  unsigned u = (k & 0x80000000u) ? (k ^ 0x80000000u) : ~k;
  return __uint_as_float(u);
}

// ============ normalize codebook + transpose w_down + bf16 codebook ============
__global__ __launch_bounds__(256) void knorm_kernel(const float* __restrict__ emb,
                                                    const float* __restrict__ w_down,
                                                    float* __restrict__ ws) {
  int k = blockIdx.x * 256 + threadIdx.x;
  const float4* src = (const float4*)emb + (size_t)k * 4;
  float4 t0 = src[0], t1 = src[1], t2 = src[2], t3 = src[3];
  float e[16] = {t0.x,t0.y,t0.z,t0.w, t1.x,t1.y,t1.z,t1.w,
                 t2.x,t2.y,t2.z,t2.w, t3.x,t3.y,t3.z,t3.w};
  float ss = 0.f;
  #pragma unroll
  for (int d = 0; d < 16; ++d) ss += e[d] * e[d];
  float dn = fmaxf(sqrtf(ss), 1e-12f);
  #pragma unroll
  for (int d = 0; d < 16; ++d) e[d] = e[d] / dn;
  float s2 = 0.f;
  #pragma unroll
  for (int d = 0; d < 16; ++d) s2 += e[d] * e[d];
  float4* dst = (float4*)(ws + WS_ENORM) + (size_t)k * 4;
  dst[0] = make_float4(e[0],e[1],e[2],e[3]);
  dst[1] = make_float4(e[4],e[5],e[6],e[7]);
  dst[2] = make_float4(e[8],e[9],e[10],e[11]);
  dst[3] = make_float4(e[12],e[13],e[14],e[15]);
  ws[WS_ENN + k] = s2;
  ws[WS_WDT + k] = w_down[(k & 15) * 256 + (k >> 4)];
  uint4 p0 = make_uint4(f2bf2(e[0],e[1]),  f2bf2(e[2],e[3]),
                        f2bf2(e[4],e[5]),  f2bf2(e[6],e[7]));
  uint4 p1 = make_uint4(f2bf2(e[8],e[9]),  f2bf2(e[10],e[11]),
                        f2bf2(e[12],e[13]),f2bf2(e[14],e[15]));
  uint4* eb = (uint4*)(ws + WS_EBF) + (size_t)k * 2;
  eb[0] = p0; eb[1] = p1;
}

// ============ down-proj + L2-normalize + bf16 copy ============
__global__ __launch_bounds__(256) void kdown_kernel(const float* __restrict__ z,
                                                    const float* __restrict__ wdt,
                                                    const float* __restrict__ b_down,
                                                    float* __restrict__ znp,
                                                    unsigned* __restrict__ znbf) {
  const int tid = threadIdx.x;
  const int n = blockIdx.x * 256 + tid;
  const int b = n >> 12;
  const int hw = n & 4095;
  const float* zp = z + (size_t)b * (CDIM * HWSZ) + hw;

  float acc[16];
  #pragma unroll
  for (int d = 0; d < 16; ++d) acc[d] = 0.f;

  #pragma unroll 16
  for (int c = 0; c < CDIM; ++c) {
    float zv = zp[(size_t)c * HWSZ];
    const float4* wr = (const float4*)(wdt + c * 16); // uniform -> s_load
    float4 w0 = wr[0], w1 = wr[1], w2 = wr[2], w3 = wr[3];
    acc[0]  = fmaf(zv, w0.x, acc[0]);  acc[1]  = fmaf(zv, w0.y, acc[1]);
    acc[2]  = fmaf(zv, w0.z, acc[2]);  acc[3]  = fmaf(zv, w0.w, acc[3]);
    acc[4]  = fmaf(zv, w1.x, acc[4]);  acc[5]  = fmaf(zv, w1.y, acc[5]);
    acc[6]  = fmaf(zv, w1.z, acc[6]);  acc[7]  = fmaf(zv, w1.w, acc[7]);
    acc[8]  = fmaf(zv, w2.x, acc[8]);  acc[9]  = fmaf(zv, w2.y, acc[9]);
    acc[10] = fmaf(zv, w2.z, acc[10]); acc[11] = fmaf(zv, w2.w, acc[11]);
    acc[12] = fmaf(zv, w3.x, acc[12]); acc[13] = fmaf(zv, w3.y, acc[13]);
    acc[14] = fmaf(zv, w3.z, acc[14]); acc[15] = fmaf(zv, w3.w, acc[15]);
  }

  #pragma unroll
  for (int d = 0; d < 16; ++d) acc[d] = acc[d] + b_down[d];
  float ss = 0.f;
  #pragma unroll
  for (int d = 0; d < 16; ++d) ss += acc[d] * acc[d];
  float dn = fmaxf(sqrtf(ss), 1e-12f);
  #pragma unroll
  for (int d = 0; d < 16; ++d) acc[d] = acc[d] / dn;

  float4* op = (float4*)znp + (size_t)n * 4;
  op[0] = make_float4(acc[0],acc[1],acc[2],acc[3]);
  op[1] = make_float4(acc[4],acc[5],acc[6],acc[7]);
  op[2] = make_float4(acc[8],acc[9],acc[10],acc[11]);
  op[3] = make_float4(acc[12],acc[13],acc[14],acc[15]);

  uint4 p0 = make_uint4(f2bf2(acc[0],acc[1]),  f2bf2(acc[2],acc[3]),
                        f2bf2(acc[4],acc[5]),  f2bf2(acc[6],acc[7]));
  uint4 p1 = make_uint4(f2bf2(acc[8],acc[9]),  f2bf2(acc[10],acc[11]),
                        f2bf2(acc[12],acc[13]),f2bf2(acc[14],acc[15]));
  uint4* zb = (uint4*)znbf + (size_t)n * 2;
  zb[0] = p0; zb[1] = p1;
}

// ============ pass 1: per-token max approx dot, K split 8 ways ============
// 32x32x16 bf16 C/D: col=lane&31, row=(reg&3)+8*(reg>>2)+4*(lane>>5) [m74]
__global__ __launch_bounds__(256) void kmin_kernel(const unsigned* __restrict__ znbf,
                                                   const unsigned* __restrict__ ebf,
                                                   unsigned* __restrict__ m1u) {
  const int lane = threadIdx.x & 63;
  const int wv = threadIdx.x >> 6;
  const int tokbase = (blockIdx.x * 4 + wv) * 32;
  const int kt0 = blockIdx.y * KTPS;
  const int hi = lane >> 5;
  const int ln = lane & 31;

  const short8* za = (const short8*)znbf;
  const short8* eb = (const short8*)ebf;
  short8 afrag = za[(size_t)(tokbase + ln) * 2 + hi];

  float m[16];
  #pragma unroll
  for (int r = 0; r < 16; ++r) m[r] = -3.4e38f;

  #pragma unroll 4
  for (int kt = 0; kt < KTPS; ++kt) {
    short8 bfrag = eb[(size_t)((kt0 + kt) * 32 + ln) * 2 + hi];
    f32x16 acc;
    #pragma unroll
    for (int r = 0; r < 16; ++r) acc[r] = 0.f;
    acc = __builtin_amdgcn_mfma_f32_32x32x16_bf16(afrag, bfrag, acc, 0, 0, 0);
    #pragma unroll
    for (int r = 0; r < 16; ++r) m[r] = fmaxf(m[r], acc[r]);
  }

  #pragma unroll
  for (int r = 0; r < 16; ++r) {
    float v = m[r];
    v = fmaxf(v, __shfl_xor(v, 16, 32));
    v = fmaxf(v, __shfl_xor(v, 8, 32));
    v = fmaxf(v, __shfl_xor(v, 4, 32));
    v = fmaxf(v, __shfl_xor(v, 2, 32));
    v = fmaxf(v, __shfl_xor(v, 1, 32));
    m[r] = v;
  }
  if (ln == 0) {
    #pragma unroll
    for (int r = 0; r < 16; ++r) {
      int row = (r & 3) + 8 * (r >> 2) + 4 * hi;
      atomicMax(m1u + tokbase + row, flipf(m[r]));
    }
  }
}

// ============ pass 2: flag candidates, exact fp32 recheck + atomicMin ============
__global__ __launch_bounds__(256) void kcand_kernel(const unsigned* __restrict__ znbf,
                                                    const unsigned* __restrict__ ebf,
                                                    const unsigned* __restrict__ m1u,
                                                    const float* __restrict__ enorm,
                                                    const float* __restrict__ ennp,
                                                    const float* __restrict__ znp,
                                                    unsigned long long* __restrict__ packp) {
  const int lane = threadIdx.x & 63;
  const int wv = threadIdx.x >> 6;
  const int tokbase = (blockIdx.x * 4 + wv) * 32;
  const int kt0 = blockIdx.y * KTPS;
  const int hi = lane >> 5;
  const int ln = lane & 31;

  const short8* za = (const short8*)znbf;
  const short8* eb = (const short8*)ebf;
  short8 afrag = za[(size_t)(tokbase + ln) * 2 + hi];

  float thr[16];
  #pragma unroll
  for (int r = 0; r < 16; ++r) {
    int row = (r & 3) + 8 * (r >> 2) + 4 * hi;
    thr[r] = unflipf(m1u[tokbase + row]) - DELTA;
  }

  for (int kt = 0; kt < KTPS; ++kt) {
    short8 bfrag = eb[(size_t)((kt0 + kt) * 32 + ln) * 2 + hi];
    f32x16 acc;
    #pragma unroll
    for (int r = 0; r < 16; ++r) acc[r] = 0.f;
    acc = __builtin_amdgcn_mfma_f32_32x32x16_bf16(afrag, bfrag, acc, 0, 0, 0);

    unsigned flags = 0u;
    #pragma unroll
    for (int r = 0; r < 16; ++r) flags |= (acc[r] >= thr[r]) ? (1u << r) : 0u;

    if (flags) {
      #pragma unroll
      for (int r = 0; r < 16; ++r) {
        if (flags & (1u << r)) {
          int row = (r & 3) + 8 * (r >> 2) + 4 * hi;
          int token = tokbase + row;
          int code = (kt0 + kt) * 32 + ln;
          const float4* znr4 = (const float4*)znp + (size_t)token * 4;
          const float4* er4  = (const float4*)enorm + (size_t)code * 4;
          float4 za0 = znr4[0], za1 = znr4[1], za2 = znr4[2], za3 = znr4[3];
          float4 eb0 = er4[0],  eb1 = er4[1],  eb2 = er4[2],  eb3 = er4[3];
          float dsc = ennp[code];
          dsc = fmaf(-2.f * za0.x, eb0.x, dsc); dsc = fmaf(-2.f * za0.y, eb0.y, dsc);
          dsc = fmaf(-2.f * za0.z, eb0.z, dsc); dsc = fmaf(-2.f * za0.w, eb0.w, dsc);
          dsc = fmaf(-2.f * za1.x, eb1.x, dsc); dsc = fmaf(-2.f * za1.y, eb1.y, dsc);
          dsc = fmaf(-2.f * za1.z, eb1.z, dsc); dsc = fmaf(-2.f * za1.w, eb1.w, dsc);
          dsc = fmaf(-2.f * za2.x, eb2.x, dsc); dsc = fmaf(-2.f * za2.y, eb2.y, dsc);
          dsc = fmaf(-2.f * za2.z, eb2.z, dsc); dsc = fmaf(-2.f * za2.w, eb2.w, dsc);
          dsc = fmaf(-2.f * za3.x, eb3.x, dsc); dsc = fmaf(-2.f * za3.y, eb3.y, dsc);
          dsc = fmaf(-2.f * za3.z, eb3.z, dsc); dsc = fmaf(-2.f * za3.w, eb3.w, dsc);
          unsigned u = __float_as_uint(dsc);
          u = (u & 0x80000000u) ? ~u : (u | 0x80000000u);
          unsigned long long key =
              ((unsigned long long)u << 32) | (unsigned)code;
          atomicMin(packp + token, key);
        }
      }
    }
  }
}

// ============ merge + scatter + loss, then LDS-staged up-proj ============
// Phase 1: 1 token/thread (merge, gather, atomics), ql -> LDS column-major.
// Phase 2: wave w owns c in [64w,64w+64); lane q owns token-quad 4q..4q+3;
//          w_up row via wave-uniform s_load; float4 stores (1KB/wave).
__global__ __launch_bounds__(256) void kfinal_kernel(const float* __restrict__ w_up,
                                                     const float* __restrict__ b_up,
                                                     const float* __restrict__ enorm,
                                                     const float* __restrict__ znp,
                                                     const unsigned long long* __restrict__ packp,
                                                     float* __restrict__ wsacc,
                                                     float* __restrict__ out) {
  __shared__ float qlds[DDIM * 256]; // [d][t], token fast axis (16 KB)
  const int tid = threadIdx.x;
  const int n0 = blockIdx.x * 256;
  const int n = n0 + tid;

  // ---- phase 1 ----
  const int bidx = (int)(unsigned)(packp[n] & 0xFFFFFFFFull);

  float zn[16];
  {
    const float4* zp = (const float4*)znp + (size_t)n * 4;
    float4 a0 = zp[0], a1 = zp[1], a2 = zp[2], a3 = zp[3];
    zn[0]=a0.x; zn[1]=a0.y; zn[2]=a0.z; zn[3]=a0.w;
    zn[4]=a1.x; zn[5]=a1.y; zn[6]=a1.z; zn[7]=a1.w;
    zn[8]=a2.x; zn[9]=a2.y; zn[10]=a2.z; zn[11]=a2.w;
    zn[12]=a3.x; zn[13]=a3.y; zn[14]=a3.z; zn[15]=a3.w;
  }
  float zq[16];
  {
    const float4* ebp = (const float4*)enorm + (size_t)bidx * 4;
    float4 q0 = ebp[0], q1 = ebp[1], q2 = ebp[2], q3 = ebp[3];
    zq[0]=q0.x; zq[1]=q0.y; zq[2]=q0.z; zq[3]=q0.w;
    zq[4]=q1.x; zq[5]=q1.y; zq[6]=q1.z; zq[7]=q1.w;
    zq[8]=q2.x; zq[9]=q2.y; zq[10]=q2.z; zq[11]=q2.w;
    zq[12]=q3.x; zq[13]=q3.y; zq[14]=q3.z; zq[15]=q3.w;
  }

  out[OFS_IDX + n] = (float)bidx;

  float ls = 0.f;
  #pragma unroll
  for (int d = 0; d < 16; ++d) { float df = zn[d] - zq[d]; ls = fmaf(df, df, ls); }

  atomicAdd(wsacc + bidx, 1.0f);
  #pragma unroll
  for (int d = 0; d < 16; ++d)
    atomicAdd(wsacc + KCOD + (size_t)bidx * 16 + d, zn[d]);

  #pragma unroll
  for (int off = 32; off > 0; off >>= 1) ls += __shfl_down(ls, off, 64);
  if ((tid & 63) == 0) atomicAdd(wsacc + KCOD + KCOD * DDIM + 0, ls);

  // ql = zn + (zq - zn) -> LDS column-major (conflict-free b32 writes)
  #pragma unroll
  for (int d = 0; d < 16; ++d) qlds[d * 256 + tid] = zn[d] + (zq[d] - zn[d]);
  __syncthreads();

  // ---- phase 2 ----
  const int wv = tid >> 6;      // wave -> c-quarter
  const int q  = tid & 63;      // lane -> token quad
  const float4* qv = (const float4*)qlds; // [16][64] float4 view
  float4 r[16];
  #pragma unroll
  for (int d = 0; d < 16; ++d) r[d] = qv[d * 64 + q];

  const int b = n0 >> 12, hw0 = n0 & 4095;
  float* opb = out + OFS_ZQ + (size_t)b * (CDIM * HWSZ) + hw0 + 4 * q;

  #pragma unroll 4
  for (int i = 0; i < 64; ++i) {
    const int c = wv * 64 + i;
    const float4* wr = (const float4*)(w_up + c * 16); // uniform -> s_load
    float4 w0 = wr[0], w1 = wr[1], w2 = wr[2], w3 = wr[3];
    float bu = b_up[c];
    float a0 = 0.f, a1 = 0.f, a2 = 0.f, a3 = 0.f;
    a0=fmaf(r[0].x,w0.x,a0); a1=fmaf(r[0].y,w0.x,a1); a2=fmaf(r[0].z,w0.x,a2); a3=fmaf(r[0].w,w0.x,a3);
    a0=fmaf(r[1].x,w0.y,a0); a1=fmaf(r[1].y,w0.y,a1); a2=fmaf(r[1].z,w0.y,a2); a3=fmaf(r[1].w,w0.y,a3);
    a0=fmaf(r[2].x,w0.z,a0); a1=fmaf(r[2].y,w0.z,a1); a2=fmaf(r[2].z,w0.z,a2); a3=fmaf(r[2].w,w0.z,a3);
    a0=fmaf(r[3].x,w0.w,a0); a1=fmaf(r[3].y,w0.w,a1); a2=fmaf(r[3].z,w0.w,a2); a3=fmaf(r[3].w,w0.w,a3);
    a0=fmaf(r[4].x,w1.x,a0); a1=fmaf(r[4].y,w1.x,a1); a2=fmaf(r[4].z,w1.x,a2); a3=fmaf(r[4].w,w1.x,a3);
    a0=fmaf(r[5].x,w1.y,a0); a1=fmaf(r[5].y,w1.y,a1); a2=fmaf(r[5].z,w1.y,a2); a3=fmaf(r[5].w,w1.y,a3);
    a0=fmaf(r[6].x,w1.z,a0); a1=fmaf(r[6].y,w1.z,a1); a2=fmaf(r[6].z,w1.z,a2); a3=fmaf(r[6].w,w1.z,a3);
    a0=fmaf(r[7].x,w1.w,a0); a1=fmaf(r[7].y,w1.w,a1); a2=fmaf(r[7].z,w1.w,a2); a3=fmaf(r[7].w,w1.w,a3);
    a0=fmaf(r[8].x,w2.x,a0); a1=fmaf(r[8].y,w2.x,a1); a2=fmaf(r[8].z,w2.x,a2); a3=fmaf(r[8].w,w2.x,a3);
    a0=fmaf(r[9].x,w2.y,a0); a1=fmaf(r[9].y,w2.y,a1); a2=fmaf(r[9].z,w2.y,a2); a3=fmaf(r[9].w,w2.y,a3);
    a0=fmaf(r[10].x,w2.z,a0); a1=fmaf(r[10].y,w2.z,a1); a2=fmaf(r[10].z,w2.z,a2); a3=fmaf(r[10].w,w2.z,a3);
    a0=fmaf(r[11].x,w2.w,a0); a1=fmaf(r[11].y,w2.w,a1); a2=fmaf(r[11].z,w2.w,a2); a3=fmaf(r[11].w,w2.w,a3);
    a0=fmaf(r[12].x,w3.x,a0); a1=fmaf(r[12].y,w3.x,a1); a2=fmaf(r[12].z,w3.x,a2); a3=fmaf(r[12].w,w3.x,a3);
    a0=fmaf(r[13].x,w3.y,a0); a1=fmaf(r[13].y,w3.y,a1); a2=fmaf(r[13].z,w3.y,a2); a3=fmaf(r[13].w,w3.y,a3);
    a0=fmaf(r[14].x,w3.z,a0); a1=fmaf(r[14].y,w3.z,a1); a2=fmaf(r[14].z,w3.z,a2); a3=fmaf(r[14].w,w3.z,a3);
    a0=fmaf(r[15].x,w3.w,a0); a1=fmaf(r[15].y,w3.w,a1); a2=fmaf(r[15].z,w3.w,a2); a3=fmaf(r[15].w,w3.w,a3);
    float4 st = make_float4(a0 + bu, a1 + bu, a2 + bu, a3 + bu);
    *(float4*)(opb + (size_t)c * HWSZ) = st;
  }
}

// ============ EMA buffers + partial sums (n, entropy) ============
__global__ __launch_bounds__(256) void kema_kernel(const float* __restrict__ cluster_size,
                                                   const float* __restrict__ embed_avg,
                                                   float* __restrict__ ws,
                                                   float* __restrict__ out) {
  const float DEC = 0.99f;
  const float OMD = (float)(1.0 - 0.99);
  const int k = blockIdx.x * 256 + threadIdx.x;
  float bcsv = ws[WS_BCS + k];
  float ncs = cluster_size[k] * DEC + OMD * bcsv;
  out[OFS_NCS + k] = ncs;
  #pragma unroll
  for (int d = 0; d < 16; ++d) {
    float nea = embed_avg[(size_t)k * 16 + d] * DEC + OMD * ws[WS_BES + (size_t)k * 16 + d];
    out[OFS_NEA + (size_t)k * 16 + d] = nea;
  }
  float p = bcsv / 65536.0f;
  float et = -p * logf(p + 1e-8f);

  __shared__ float r1[4], r2[4];
  float v1 = ncs, v2 = et;
  #pragma unroll
  for (int off = 32; off > 0; off >>= 1) {
    v1 += __shfl_down(v1, off, 64);
    v2 += __shfl_down(v2, off, 64);
  }
  int lane = threadIdx.x & 63, w = threadIdx.x >> 6;
  if (lane == 0) { r1[w] = v1; r2[w] = v2; }
  __syncthreads();
  if (threadIdx.x == 0) {
    atomicAdd(ws + WS_SCAL + 1, (r1[0] + r1[1]) + (r1[2] + r1[3]));
    atomicAdd(ws + WS_SCAL + 2, (r2[0] + r2[1]) + (r2[2] + r2[3]));
  }
}

// ============ new_embedding + scalar outputs ============
__global__ __launch_bounds__(256) void kemb_kernel(const float* __restrict__ ws,
                                                   float* __restrict__ out) {
  const float KEPS = (float)(4096.0 * 1e-5);
  const int k = blockIdx.x * 256 + threadIdx.x;
  float n = ws[WS_SCAL + 1];
  float ncs = out[OFS_NCS + k];
  float cs = (ncs + 1e-5f) / (n + KEPS) * n;
  #pragma unroll
  for (int d = 0; d < 16; ++d)
    out[OFS_NE + (size_t)k * 16 + d] = out[OFS_NEA + (size_t)k * 16 + d] / cs;
  if (k == 0) {
    out[OFS_LOSS] = 0.25f * (ws[WS_SCAL + 0] / 1048576.0f);
    out[OFS_ENT]  = (float)8.317766166719343 - ws[WS_SCAL + 2];
  }
}

extern "C" void kernel_launch(void* const* d_in, const int* in_sizes, int n_in,
                              void* d_out, int out_size, void* d_ws, size_t ws_size,
                              hipStream_t stream) {
  const float* z        = (const float*)d_in[0];
  const float* w_down   = (const float*)d_in[1];
  const float* b_down   = (const float*)d_in[2];
  const float* w_up     = (const float*)d_in[3];
  const float* b_up     = (const float*)d_in[4];
  const float* emb      = (const float*)d_in[5];
  const float* csz      = (const float*)d_in[6];
  const float* eavg     = (const float*)d_in[7];
  float* out = (float*)d_out;
  float* ws  = (float*)d_ws;

  // zero m1 (flipped-uint identity) + bcs + bes + scal in one shot
  hipMemsetAsync(ws + WS_M1, 0,
                 (size_t)(NTOK + KCOD + KCOD*DDIM + 8) * sizeof(float), stream);
  hipMemsetAsync(ws + WS_PACK, 0xFF, (size_t)NTOK * 8, stream);

  knorm_kernel<<<KCOD / 256, 256, 0, stream>>>(emb, w_down, ws);
  kdown_kernel<<<NTOK / 256, 256, 0, stream>>>(z, ws + WS_WDT, b_down,
                                               ws + WS_ZN, (unsigned*)(ws + WS_ZNBF));
  kmin_kernel<<<dim3(NTOK / 128, KSPLIT2), 256, 0, stream>>>(
      (const unsigned*)(ws + WS_ZNBF), (const unsigned*)(ws + WS_EBF),
      (unsigned*)(ws + WS_M1));
  kcand_kernel<<<dim3(NTOK / 128, KSPLIT2), 256, 0, stream>>>(
      (const unsigned*)(ws + WS_ZNBF), (const unsigned*)(ws + WS_EBF),
      (const unsigned*)(ws + WS_M1), ws + WS_ENORM, ws + WS_ENN, ws + WS_ZN,
      (unsigned long long*)(ws + WS_PACK));
  kfinal_kernel<<<NTOK / 256, 256, 0, stream>>>(
      w_up, b_up, ws + WS_ENORM, ws + WS_ZN,
      (const unsigned long long*)(ws + WS_PACK), ws + WS_BCS, out);
  kema_kernel<<<KCOD / 256, 256, 0, stream>>>(csz, eavg, ws, out);
  kemb_kernel<<<KCOD / 256, 256, 0, stream>>>(ws, out);
}